// Round 1
// baseline (148.448 us; speedup 1.0000x reference)
//
#include <hip/hip_runtime.h>
#include <stdint.h>

typedef unsigned short u16;
typedef __attribute__((ext_vector_type(8))) __bf16 bf16x8;
typedef __attribute__((ext_vector_type(4))) float f32x4;

#define AS1 __attribute__((address_space(1)))
#define AS3 __attribute__((address_space(3)))

__device__ __forceinline__ u16 f2bf(float f) {
  uint32_t u = __builtin_bit_cast(uint32_t, f);
  u += 0x7FFFu + ((u >> 16) & 1u);   // RNE; inputs are finite
  return (u16)(u >> 16);
}
__device__ __forceinline__ float bf2f(u16 h) {
  uint32_t u = ((uint32_t)h) << 16;
  return __builtin_bit_cast(float, u);
}
__device__ __forceinline__ void gload16(const void* g, void* l) {
  __builtin_amdgcn_global_load_lds((AS1 void*)g, (AS3 void*)l, 16, 0, 0);
}

// ---- x: f32 -> bf16, vectorized ----
__global__ __launch_bounds__(256) void cvt_f32_bf16(const float4* __restrict__ in,
                                                    ushort4* __restrict__ out, int n4) {
  int i = blockIdx.x * 256 + threadIdx.x;
  if (i >= n4) return;
  float4 v = in[i];
  ushort4 o;
  o.x = f2bf(v.x); o.y = f2bf(v.y); o.z = f2bf(v.z); o.w = f2bf(v.w);
  out[i] = o;
}

// ---- w [R][C] f32 -> wt [C][R] bf16 (transpose + convert) ----
__global__ __launch_bounds__(256) void transpose_cvt(const float* __restrict__ w,
                                                     u16* __restrict__ wt, int R, int C) {
  __shared__ u16 tile[32][33];
  int c0 = blockIdx.x * 32, r0 = blockIdx.y * 32;
  int tx = threadIdx.x & 31, ty = threadIdx.x >> 5;
  #pragma unroll
  for (int rr = ty; rr < 32; rr += 8)
    tile[rr][tx] = f2bf(w[(size_t)(r0 + rr) * C + c0 + tx]);
  __syncthreads();
  #pragma unroll
  for (int rr = ty; rr < 32; rr += 8)
    wt[(size_t)(c0 + rr) * R + r0 + tx] = tile[tx][rr];
}

// ---- bf16 GEMM, m97 structure: 128x128 tile, 4 waves (2x2), BK=32 ----
// C[row,col] = sum_k A[row,k] * Bt[col,k]  (+bias), A/Bt bf16 row-major
template<bool OUT_F32, bool BIAS>
__global__ __launch_bounds__(256) void gemm_bt(
    const u16* __restrict__ A, int lda, long long strideA,
    const u16* __restrict__ Bt, int ldb, long long strideB,
    void* __restrict__ C, int ldc, long long strideC,
    const float* __restrict__ bias, int K)
{
  const int bcol = blockIdx.x * 128;
  const int brow = blockIdx.y * 128;
  const int bz = blockIdx.z;
  const u16* Ab = A + (size_t)bz * strideA;
  const u16* Bb = Bt + (size_t)bz * strideB;

  __shared__ u16 Asm[128 * 32];
  __shared__ u16 Bsm[128 * 32];

  const int tid = threadIdx.x;
  const int wid = tid >> 6;
  const int lane = tid & 63;
  const int fr = lane & 15, fq = lane >> 4;
  const int wr = wid >> 1, wc = wid & 1;
  const int skel = (lane & 3) * 8;        // k element within 32 (16B granules)

  f32x4 acc[4][4];
  #pragma unroll
  for (int m = 0; m < 4; ++m)
    #pragma unroll
    for (int n = 0; n < 4; ++n)
      acc[m][n] = (f32x4)0.0f;

  for (int kt = 0; kt < K; kt += 32) {
    // stage 128x32 A-tile and Bt-tile: each wave issues 2x1024B per tile
    #pragma unroll
    for (int q = 0; q < 2; ++q) {
      int chunk = wid * 2 + q;            // 0..7, 16 rows each
      int row = chunk * 16 + (lane >> 2);
      gload16(Ab + (size_t)(brow + row) * lda + kt + skel, &Asm[chunk * 512]);
      gload16(Bb + (size_t)(bcol + row) * ldb + kt + skel, &Bsm[chunk * 512]);
    }
    __syncthreads();   // compiler drains vmcnt before s_barrier

    bf16x8 af[4], bg[4];
    #pragma unroll
    for (int m = 0; m < 4; ++m)
      af[m] = *(const bf16x8*)&Asm[(wr * 64 + m * 16 + fr) * 32 + fq * 8];
    #pragma unroll
    for (int n = 0; n < 4; ++n)
      bg[n] = *(const bf16x8*)&Bsm[(wc * 64 + n * 16 + fr) * 32 + fq * 8];
    #pragma unroll
    for (int m = 0; m < 4; ++m)
      #pragma unroll
      for (int n = 0; n < 4; ++n)
        acc[m][n] = __builtin_amdgcn_mfma_f32_16x16x32_bf16(af[m], bg[n], acc[m][n], 0, 0, 0);
    __syncthreads();
  }

  #pragma unroll
  for (int m = 0; m < 4; ++m) {
    #pragma unroll
    for (int n = 0; n < 4; ++n) {
      #pragma unroll
      for (int j = 0; j < 4; ++j) {
        int row = brow + wr * 64 + m * 16 + fq * 4 + j;
        int col = bcol + wc * 64 + n * 16 + fr;
        float v = acc[m][n][j];
        if constexpr (OUT_F32) {
          if constexpr (BIAS) v += bias[col];
          ((float*)C)[(size_t)bz * strideC + (size_t)row * ldc + col] = v;
        } else {
          ((u16*)C)[(size_t)bz * strideC + (size_t)row * ldc + col] = f2bf(v);
        }
      }
    }
  }
}

// ---- per-(b,h) partial K^T V over an N-slice; Mpart[bh][s][64][64] f32 ----
#define KTV_SPLIT 16
__global__ __launch_bounds__(256) void ktv_partial(const u16* __restrict__ qkv,
                                                   float* __restrict__ Mpart) {
  const int s = blockIdx.x;    // 0..15
  const int bh = blockIdx.y;   // 0..31
  const int b = bh >> 3, h = bh & 7;
  const int t = threadIdx.x;
  __shared__ u16 Ks[8][64];
  __shared__ u16 Vs[8][64];
  const int d = t >> 2;
  const int e0 = (t & 3) * 16;
  float acc[16];
  #pragma unroll
  for (int j = 0; j < 16; ++j) acc[j] = 0.f;

  const int nn_l = t >> 5;            // row within 8-chunk this thread loads
  const int half = (t >> 4) & 1;      // 0:K, 1:V
  const int col = (t & 15) * 4;
  const u16* gbase = qkv + (size_t)b * 2048 * 1536 + 512 + half * 512 + h * 64 + col;
  u16* ldst = half ? &Vs[nn_l][col] : &Ks[nn_l][col];

  const int seg = 2048 / KTV_SPLIT;   // 128
  for (int c = 0; c < seg / 8; ++c) {
    int n0 = s * seg + c * 8;
    ushort4 vv = *(const ushort4*)(gbase + (size_t)(n0 + nn_l) * 1536);
    __syncthreads();
    *(ushort4*)ldst = vv;
    __syncthreads();
    #pragma unroll
    for (int nn = 0; nn < 8; ++nn) {
      float kd = bf2f(Ks[nn][d]);
      #pragma unroll
      for (int j = 0; j < 16; ++j)
        acc[j] += kd * bf2f(Vs[nn][e0 + j]);
    }
  }
  float* dst = Mpart + ((size_t)bh * KTV_SPLIT + s) * 4096 + d * 64 + e0;
  #pragma unroll
  for (int j = 0; j < 16; ++j) dst[j] = acc[j];
}

// ---- Pt[b][c][h*64+d] = scale * sum_e M_bh[d][e] * w_out[h*64+e][c], bf16 ----
__global__ __launch_bounds__(256) void make_pt(const float* __restrict__ Mpart,
                                               const float* __restrict__ w_out,
                                               u16* __restrict__ Pt, float scale) {
  const int quarter = blockIdx.x;   // 0..3  (column quarter)
  const int bh = blockIdx.y;        // 0..31
  const int b = bh >> 3, h = bh & 7;
  const int t = threadIdx.x;
  __shared__ float Msm[4096];
  for (int i = t; i < 4096; i += 256) {
    float sum = 0.f;
    for (int p = 0; p < KTV_SPLIT; ++p)
      sum += Mpart[((size_t)bh * KTV_SPLIT + p) * 4096 + i];
    Msm[i] = sum * scale;
  }
  __syncthreads();
  const int d = t >> 2;
  const int cbase = quarter * 128 + (t & 3) * 32;
  u16* pdst = Pt + (size_t)b * 512 * 512;
  #pragma unroll
  for (int cc = 0; cc < 32; cc += 16) {
    float4 a4[4];
    #pragma unroll
    for (int r = 0; r < 4; ++r) { a4[r].x = 0.f; a4[r].y = 0.f; a4[r].z = 0.f; a4[r].w = 0.f; }
    for (int e = 0; e < 64; ++e) {
      float m = Msm[d * 64 + e];
      const float4* w4 = (const float4*)(w_out + (size_t)(h * 64 + e) * 512 + cbase + cc);
      #pragma unroll
      for (int r = 0; r < 4; ++r) {
        float4 wv = w4[r];
        a4[r].x += m * wv.x; a4[r].y += m * wv.y; a4[r].z += m * wv.z; a4[r].w += m * wv.w;
      }
    }
    #pragma unroll
    for (int r = 0; r < 4; ++r) {
      int c = cbase + cc + r * 4;
      pdst[(size_t)(c + 0) * 512 + h * 64 + d] = f2bf(a4[r].x);
      pdst[(size_t)(c + 1) * 512 + h * 64 + d] = f2bf(a4[r].y);
      pdst[(size_t)(c + 2) * 512 + h * 64 + d] = f2bf(a4[r].z);
      pdst[(size_t)(c + 3) * 512 + h * 64 + d] = f2bf(a4[r].w);
    }
  }
}

extern "C" void kernel_launch(void* const* d_in, const int* in_sizes, int n_in,
                              void* d_out, int out_size, void* d_ws, size_t ws_size,
                              hipStream_t stream) {
  const float* x     = (const float*)d_in[0];   // [4,2048,512]
  const float* w_qkv = (const float*)d_in[1];   // [512,1536]
  const float* w_out = (const float*)d_in[2];   // [512,512]
  const float* b_out = (const float*)d_in[3];   // [512]
  float* out = (float*)d_out;                   // [4,2048,512] f32
  char* ws = (char*)d_ws;

  u16*   x_bf   = (u16*)(ws);                    // 8 MiB  [8192][512] bf16
  u16*   wqkv_t = (u16*)(ws + (8ll << 20));      // 1.5 MiB [1536][512] bf16 (w_qkv^T)
  u16*   qkv    = (u16*)(ws + (10ll << 20));     // 24 MiB [8192][1536] bf16
  float* Mpart  = (float*)(ws + (34ll << 20));   // 8 MiB  [32][16][64][64] f32
  u16*   Pt     = (u16*)(ws + (42ll << 20));     // 2 MiB  [4][512][512] bf16 (P^T per b)

  // 1) x -> bf16
  cvt_f32_bf16<<<dim3(4096), dim3(256), 0, stream>>>(
      (const float4*)x, (ushort4*)x_bf, 8192 * 512 / 4);
  // 2) w_qkv -> transposed bf16
  transpose_cvt<<<dim3(48, 16), dim3(256), 0, stream>>>(w_qkv, wqkv_t, 512, 1536);
  // 3) qkv = x @ w_qkv   (M=8192, N=1536, K=512), bf16 out
  gemm_bt<false, false><<<dim3(12, 64, 1), dim3(256), 0, stream>>>(
      x_bf, 512, 0ll, wqkv_t, 512, 0ll, qkv, 1536, 0ll, nullptr, 512);
  // 4) partial K^T V per (b,h)
  ktv_partial<<<dim3(KTV_SPLIT, 32), dim3(256), 0, stream>>>(qkv, Mpart);
  // 5) Pt = (scale * M @ W_out)^T, stacked over heads, per b
  make_pt<<<dim3(4, 32), dim3(256), 0, stream>>>(Mpart, w_out, Pt, 0.125f / 2048.0f);
  // 6) out = Q_cat @ P + b_out  (per b: M=2048, N=512, K=512), f32 out
  gemm_bt<true, true><<<dim3(4, 16, 4), dim3(256), 0, stream>>>(
      qkv, 1536, 2048ll * 1536, Pt, 512, 512ll * 512, out, 512, 2048ll * 512, b_out, 512);
}

// Round 2
// 96.464 us; speedup vs baseline: 1.5389x; 1.5389x over previous
//
#include <hip/hip_runtime.h>
#include <stdint.h>

typedef unsigned short u16;
typedef __attribute__((ext_vector_type(8))) __bf16 bf16x8;
typedef __attribute__((ext_vector_type(4))) float f32x4;

#define AS1 __attribute__((address_space(1)))
#define AS3 __attribute__((address_space(3)))

__device__ __forceinline__ u16 f2bf(float f) {
  uint32_t u = __builtin_bit_cast(uint32_t, f);
  u += 0x7FFFu + ((u >> 16) & 1u);   // RNE; inputs are finite
  return (u16)(u >> 16);
}
__device__ __forceinline__ float bf2f(u16 h) {
  uint32_t u = ((uint32_t)h) << 16;
  return __builtin_bit_cast(float, u);
}
__device__ __forceinline__ void gload16(const void* g, void* l) {
  __builtin_amdgcn_global_load_lds((AS1 void*)g, (AS3 void*)l, 16, 0, 0);
}

// ---- x: f32 -> bf16, vectorized ----
__global__ __launch_bounds__(256) void cvt_f32_bf16(const float4* __restrict__ in,
                                                    ushort4* __restrict__ out, int n4) {
  int i = blockIdx.x * 256 + threadIdx.x;
  if (i >= n4) return;
  float4 v = in[i];
  ushort4 o;
  o.x = f2bf(v.x); o.y = f2bf(v.y); o.z = f2bf(v.z); o.w = f2bf(v.w);
  out[i] = o;
}

// ---- w [R][C] f32 -> wt [C][R] bf16 (transpose + convert) ----
__global__ __launch_bounds__(256) void transpose_cvt(const float* __restrict__ w,
                                                     u16* __restrict__ wt, int R, int C) {
  __shared__ u16 tile[32][33];
  int c0 = blockIdx.x * 32, r0 = blockIdx.y * 32;
  int tx = threadIdx.x & 31, ty = threadIdx.x >> 5;
  #pragma unroll
  for (int rr = ty; rr < 32; rr += 8)
    tile[rr][tx] = f2bf(w[(size_t)(r0 + rr) * C + c0 + tx]);
  __syncthreads();
  #pragma unroll
  for (int rr = ty; rr < 32; rr += 8)
    wt[(size_t)(c0 + rr) * R + r0 + tx] = tile[tx][rr];
}

// ---- bf16 GEMM, m97 structure: 128x128 tile, 4 waves (2x2), BK=32 ----
// C[row,col] = sum_k A[row,k] * Bt[col,k]  (+bias), A/Bt bf16 row-major
template<bool OUT_F32, bool BIAS>
__global__ __launch_bounds__(256) void gemm_bt(
    const u16* __restrict__ A, int lda, long long strideA,
    const u16* __restrict__ Bt, int ldb, long long strideB,
    void* __restrict__ C, int ldc, long long strideC,
    const float* __restrict__ bias, int K)
{
  const int bcol = blockIdx.x * 128;
  const int brow = blockIdx.y * 128;
  const int bz = blockIdx.z;
  const u16* Ab = A + (size_t)bz * strideA;
  const u16* Bb = Bt + (size_t)bz * strideB;

  __shared__ u16 Asm[128 * 32];
  __shared__ u16 Bsm[128 * 32];

  const int tid = threadIdx.x;
  const int wid = tid >> 6;
  const int lane = tid & 63;
  const int fr = lane & 15, fq = lane >> 4;
  const int wr = wid >> 1, wc = wid & 1;
  const int skel = (lane & 3) * 8;        // k element within 32 (16B granules)

  f32x4 acc[4][4];
  #pragma unroll
  for (int m = 0; m < 4; ++m)
    #pragma unroll
    for (int n = 0; n < 4; ++n)
      acc[m][n] = (f32x4)0.0f;

  for (int kt = 0; kt < K; kt += 32) {
    // stage 128x32 A-tile and Bt-tile: each wave issues 2x1024B per tile
    #pragma unroll
    for (int q = 0; q < 2; ++q) {
      int chunk = wid * 2 + q;            // 0..7, 16 rows each
      int row = chunk * 16 + (lane >> 2);
      gload16(Ab + (size_t)(brow + row) * lda + kt + skel, &Asm[chunk * 512]);
      gload16(Bb + (size_t)(bcol + row) * ldb + kt + skel, &Bsm[chunk * 512]);
    }
    __syncthreads();   // compiler drains vmcnt before s_barrier

    bf16x8 af[4], bg[4];
    #pragma unroll
    for (int m = 0; m < 4; ++m)
      af[m] = *(const bf16x8*)&Asm[(wr * 64 + m * 16 + fr) * 32 + fq * 8];
    #pragma unroll
    for (int n = 0; n < 4; ++n)
      bg[n] = *(const bf16x8*)&Bsm[(wc * 64 + n * 16 + fr) * 32 + fq * 8];
    #pragma unroll
    for (int m = 0; m < 4; ++m)
      #pragma unroll
      for (int n = 0; n < 4; ++n)
        acc[m][n] = __builtin_amdgcn_mfma_f32_16x16x32_bf16(af[m], bg[n], acc[m][n], 0, 0, 0);
    __syncthreads();
  }

  #pragma unroll
  for (int m = 0; m < 4; ++m) {
    #pragma unroll
    for (int n = 0; n < 4; ++n) {
      #pragma unroll
      for (int j = 0; j < 4; ++j) {
        int row = brow + wr * 64 + m * 16 + fq * 4 + j;
        int col = bcol + wc * 64 + n * 16 + fr;
        float v = acc[m][n][j];
        if constexpr (OUT_F32) {
          if constexpr (BIAS) v += bias[col];
          ((float*)C)[(size_t)bz * strideC + (size_t)row * ldc + col] = v;
        } else {
          ((u16*)C)[(size_t)bz * strideC + (size_t)row * ldc + col] = f2bf(v);
        }
      }
    }
  }
}

// ---- per-(b,h) partial K^T V over an N-slice; Mpart[bh][s][64][64] f32 ----
#define KTV_SPLIT 16
__global__ __launch_bounds__(256) void ktv_partial(const u16* __restrict__ qkv,
                                                   float* __restrict__ Mpart) {
  const int s = blockIdx.x;    // 0..15
  const int bh = blockIdx.y;   // 0..31
  const int b = bh >> 3, h = bh & 7;
  const int t = threadIdx.x;
  __shared__ u16 Ks[8][64];
  __shared__ u16 Vs[8][64];
  const int d = t >> 2;
  const int e0 = (t & 3) * 16;
  float acc[16];
  #pragma unroll
  for (int j = 0; j < 16; ++j) acc[j] = 0.f;

  const int nn_l = t >> 5;            // row within 8-chunk this thread loads
  const int half = (t >> 4) & 1;      // 0:K, 1:V
  const int col = (t & 15) * 4;
  const u16* gbase = qkv + (size_t)b * 2048 * 1536 + 512 + half * 512 + h * 64 + col;
  u16* ldst = half ? &Vs[nn_l][col] : &Ks[nn_l][col];

  const int seg = 2048 / KTV_SPLIT;   // 128
  for (int c = 0; c < seg / 8; ++c) {
    int n0 = s * seg + c * 8;
    ushort4 vv = *(const ushort4*)(gbase + (size_t)(n0 + nn_l) * 1536);
    __syncthreads();
    *(ushort4*)ldst = vv;
    __syncthreads();
    #pragma unroll
    for (int nn = 0; nn < 8; ++nn) {
      float kd = bf2f(Ks[nn][d]);
      #pragma unroll
      for (int j = 0; j < 16; ++j)
        acc[j] += kd * bf2f(Vs[nn][e0 + j]);
    }
  }
  float* dst = Mpart + ((size_t)bh * KTV_SPLIT + s) * 4096 + d * 64 + e0;
  #pragma unroll
  for (int j = 0; j < 16; ++j) dst[j] = acc[j];
}

// ---- M[bh][d][e] = scale * sum_p Mpart[bh][p][d][e]  (fully parallel) ----
__global__ __launch_bounds__(256) void reduce_m(const float* __restrict__ Mpart,
                                                float* __restrict__ M, float scale) {
  int i = blockIdx.x * 256 + threadIdx.x;      // 0 .. 32*4096-1
  int bh = i >> 12;
  int off = i & 4095;
  const float* src = Mpart + ((size_t)bh * KTV_SPLIT) * 4096 + off;
  float s = 0.f;
  #pragma unroll
  for (int p = 0; p < KTV_SPLIT; ++p) s += src[(size_t)p * 4096];
  M[i] = s * scale;
}

// ---- Pt[b][c][h*64+d] = sum_e M[bh][d][e] * w_out[h*64+e][c], bf16 ----
// grid: (4 c-tiles, 32 bh). Block stages M_h (16KB) in LDS; each thread
// owns one c and a 32-wide d-range; w_out loads coalesced, M broadcast.
__global__ __launch_bounds__(256) void make_pt2(const float* __restrict__ M,
                                                const float* __restrict__ w_out,
                                                u16* __restrict__ Pt) {
  const int ct = blockIdx.x;      // 0..3
  const int bh = blockIdx.y;      // 0..31
  const int b = bh >> 3, h = bh & 7;
  const int t = threadIdx.x;
  __shared__ float Msm[64][64];
  {
    const float4* src = (const float4*)(M + (size_t)bh * 4096);
    float4* dst = (float4*)&Msm[0][0];
    #pragma unroll
    for (int r = 0; r < 4; ++r) dst[t + r * 256] = src[t + r * 256];
  }
  __syncthreads();
  const int c = ct * 128 + (t & 127);
  const int d0 = (t >> 7) * 32;
  float acc[32];
  #pragma unroll
  for (int j = 0; j < 32; ++j) acc[j] = 0.f;
  const float* wcol = w_out + (size_t)h * 64 * 512 + c;
  #pragma unroll 4
  for (int e = 0; e < 64; ++e) {
    float w = wcol[(size_t)e * 512];
    #pragma unroll
    for (int j = 0; j < 32; ++j)
      acc[j] += Msm[d0 + j][e] * w;
  }
  ushort4 ov[8];
  #pragma unroll
  for (int r = 0; r < 8; ++r) {
    ov[r].x = f2bf(acc[r * 4 + 0]);
    ov[r].y = f2bf(acc[r * 4 + 1]);
    ov[r].z = f2bf(acc[r * 4 + 2]);
    ov[r].w = f2bf(acc[r * 4 + 3]);
  }
  ushort4* dst = (ushort4*)(Pt + (size_t)b * 512 * 512 + (size_t)c * 512 + h * 64 + d0);
  #pragma unroll
  for (int r = 0; r < 8; ++r) dst[r] = ov[r];
}

extern "C" void kernel_launch(void* const* d_in, const int* in_sizes, int n_in,
                              void* d_out, int out_size, void* d_ws, size_t ws_size,
                              hipStream_t stream) {
  const float* x     = (const float*)d_in[0];   // [4,2048,512]
  const float* w_qkv = (const float*)d_in[1];   // [512,1536]
  const float* w_out = (const float*)d_in[2];   // [512,512]
  const float* b_out = (const float*)d_in[3];   // [512]
  float* out = (float*)d_out;                   // [4,2048,512] f32
  char* ws = (char*)d_ws;

  u16*   x_bf   = (u16*)(ws);                    // 8 MiB  [8192][512] bf16 (dead after GEMM1)
  u16*   wqkv_t = (u16*)(ws + (8ll << 20));      // 1.5 MiB [1536][512] bf16 (w_qkv^T)
  u16*   qkv    = (u16*)(ws + (10ll << 20));     // 24 MiB [8192][1536] bf16
  float* Mpart  = (float*)(ws + (34ll << 20));   // 8 MiB  [32][16][64][64] f32
  u16*   Pt     = (u16*)(ws + (42ll << 20));     // 2 MiB  [4][512][512] bf16 (P^T per b)
  float* M      = (float*)(ws);                  // 0.5 MiB [32][64][64] f32 (reuses x_bf)

  // 1) x -> bf16
  cvt_f32_bf16<<<dim3(4096), dim3(256), 0, stream>>>(
      (const float4*)x, (ushort4*)x_bf, 8192 * 512 / 4);
  // 2) w_qkv -> transposed bf16
  transpose_cvt<<<dim3(48, 16), dim3(256), 0, stream>>>(w_qkv, wqkv_t, 512, 1536);
  // 3) qkv = x @ w_qkv   (M=8192, N=1536, K=512), bf16 out
  gemm_bt<false, false><<<dim3(12, 64, 1), dim3(256), 0, stream>>>(
      x_bf, 512, 0ll, wqkv_t, 512, 0ll, qkv, 1536, 0ll, nullptr, 512);
  // 4) partial K^T V per (b,h)
  ktv_partial<<<dim3(KTV_SPLIT, 32), dim3(256), 0, stream>>>(qkv, Mpart);
  // 5a) reduce partials (x_bf region is dead now)
  reduce_m<<<dim3(512), dim3(256), 0, stream>>>(Mpart, M, 0.125f / 2048.0f);
  // 5b) Pt = (M @ W_out)^T per (b,h)
  make_pt2<<<dim3(4, 32), dim3(256), 0, stream>>>(M, w_out, Pt);
  // 6) out = Q_cat @ P + b_out  (per b: M=2048, N=512, K=512), f32 out
  gemm_bt<true, true><<<dim3(4, 16, 4), dim3(256), 0, stream>>>(
      qkv, 1536, 2048ll * 1536, Pt, 512, 512ll * 512, out, 512, 2048ll * 512, b_out, 512);
}

// Round 3
// 74.024 us; speedup vs baseline: 2.0054x; 1.3031x over previous
//
#include <hip/hip_runtime.h>
#include <stdint.h>

typedef unsigned short u16;
typedef __attribute__((ext_vector_type(8))) __bf16 bf16x8;
typedef __attribute__((ext_vector_type(8))) unsigned short u16x8;
typedef __attribute__((ext_vector_type(4))) float f32x4;

#define AS1 __attribute__((address_space(1)))
#define AS3 __attribute__((address_space(3)))

__device__ __forceinline__ u16 f2bf(float f) {
  uint32_t u = __builtin_bit_cast(uint32_t, f);
  u += 0x7FFFu + ((u >> 16) & 1u);   // RNE; inputs are finite
  return (u16)(u >> 16);
}
__device__ __forceinline__ float bf2f(u16 h) {
  uint32_t u = ((uint32_t)h) << 16;
  return __builtin_bit_cast(float, u);
}
__device__ __forceinline__ void gload16(const void* g, void* l) {
  __builtin_amdgcn_global_load_lds((AS1 void*)g, (AS3 void*)l, 16, 0, 0);
}

// ---- fused: x f32->bf16 (blocks 0..4095) + w_qkv transpose (blocks 4096..4863) ----
__global__ __launch_bounds__(256) void prep(const float4* __restrict__ x,
                                            ushort4* __restrict__ x_bf,
                                            const float* __restrict__ w,
                                            u16* __restrict__ wt) {
  __shared__ u16 tile[32][33];
  const int bid = blockIdx.x;
  if (bid < 4096) {
    int i = bid * 256 + threadIdx.x;
    float4 v = x[i];
    ushort4 o;
    o.x = f2bf(v.x); o.y = f2bf(v.y); o.z = f2bf(v.z); o.w = f2bf(v.w);
    x_bf[i] = o;
  } else {
    int tb = bid - 4096;                 // 0..767 over [512][1536]
    int c0 = (tb % 48) * 32, r0 = (tb / 48) * 32;
    int tx = threadIdx.x & 31, ty = threadIdx.x >> 5;
    #pragma unroll
    for (int rr = ty; rr < 32; rr += 8)
      tile[rr][tx] = f2bf(w[(size_t)(r0 + rr) * 1536 + c0 + tx]);
    __syncthreads();
    #pragma unroll
    for (int rr = ty; rr < 32; rr += 8)
      wt[(size_t)(c0 + rr) * 512 + r0 + tx] = tile[tx][rr];
  }
}

// ---- bf16 GEMM, m97 structure: 128xBN tile, 4 waves, BK=32 ----
// C[row,col] = sum_k A[row,k] * Bt[col,k]  (+bias). BN = NFRAG*32.
template<bool OUT_F32, bool BIAS, int NFRAG>
__global__ __launch_bounds__(256) void gemm_bt(
    const u16* __restrict__ A, int lda, long long strideA,
    const u16* __restrict__ Bt, int ldb, long long strideB,
    void* __restrict__ C, int ldc, long long strideC,
    const float* __restrict__ bias, int K)
{
  constexpr int BN = NFRAG * 32;
  const int bcol = blockIdx.x * BN;
  const int brow = blockIdx.y * 128;
  const int bz = blockIdx.z;
  const u16* Ab = A + (size_t)bz * strideA;
  const u16* Bb = Bt + (size_t)bz * strideB;

  __shared__ u16 Asm[128 * 32];
  __shared__ u16 Bsm[BN * 32];

  const int tid = threadIdx.x;
  const int wid = tid >> 6;
  const int lane = tid & 63;
  const int fr = lane & 15, fq = lane >> 4;
  const int wr = wid >> 1, wc = wid & 1;
  const int skel = (lane & 3) * 8;        // k element within 32 (16B granules)

  f32x4 acc[4][NFRAG];
  #pragma unroll
  for (int m = 0; m < 4; ++m)
    #pragma unroll
    for (int n = 0; n < NFRAG; ++n)
      acc[m][n] = (f32x4)0.0f;

  for (int kt = 0; kt < K; kt += 32) {
    #pragma unroll
    for (int q = 0; q < 2; ++q) {
      int chunk = wid * 2 + q;            // 0..7, 16 rows each
      int row = chunk * 16 + (lane >> 2);
      gload16(Ab + (size_t)(brow + row) * lda + kt + skel, &Asm[chunk * 512]);
    }
    #pragma unroll
    for (int q = 0; q < BN / 64; ++q) {
      int chunk = wid * (BN / 64) + q;
      int row = chunk * 16 + (lane >> 2);
      gload16(Bb + (size_t)(bcol + row) * ldb + kt + skel, &Bsm[chunk * 512]);
    }
    __syncthreads();   // compiler drains vmcnt before s_barrier

    bf16x8 af[4], bg[NFRAG];
    #pragma unroll
    for (int m = 0; m < 4; ++m)
      af[m] = *(const bf16x8*)&Asm[(wr * 64 + m * 16 + fr) * 32 + fq * 8];
    #pragma unroll
    for (int n = 0; n < NFRAG; ++n)
      bg[n] = *(const bf16x8*)&Bsm[(wc * (NFRAG * 16) + n * 16 + fr) * 32 + fq * 8];
    #pragma unroll
    for (int m = 0; m < 4; ++m)
      #pragma unroll
      for (int n = 0; n < NFRAG; ++n)
        acc[m][n] = __builtin_amdgcn_mfma_f32_16x16x32_bf16(af[m], bg[n], acc[m][n], 0, 0, 0);
    __syncthreads();
  }

  #pragma unroll
  for (int m = 0; m < 4; ++m) {
    #pragma unroll
    for (int n = 0; n < NFRAG; ++n) {
      #pragma unroll
      for (int j = 0; j < 4; ++j) {
        int row = brow + wr * 64 + m * 16 + fq * 4 + j;
        int col = bcol + wc * (NFRAG * 16) + n * 16 + fr;
        float v = acc[m][n][j];
        if constexpr (OUT_F32) {
          if constexpr (BIAS) v += bias[col];
          ((float*)C)[(size_t)bz * strideC + (size_t)row * ldc + col] = v;
        } else {
          ((u16*)C)[(size_t)bz * strideC + (size_t)row * ldc + col] = f2bf(v);
        }
      }
    }
  }
}

// ---- per-(b,h) partial K^T V over a 128-row N-slice; Mpart[bh][s][64][64] f32 ----
#define KTV_SPLIT 16
__device__ __forceinline__ void ktv_load(const u16* __restrict__ base, int n0, int h, int t,
                                         u16x8& a, u16x8& b) {
  int row0 = t >> 4, part0 = t & 15;
  int col0 = (part0 < 8) ? (512 + h * 64 + part0 * 8) : (1024 + h * 64 + (part0 - 8) * 8);
  a = *(const u16x8*)(base + (size_t)(n0 + row0) * 1536 + col0);
  int idx1 = 256 + t;
  int row1 = idx1 >> 4, part1 = idx1 & 15;
  int col1 = (part1 < 8) ? (512 + h * 64 + part1 * 8) : (1024 + h * 64 + (part1 - 8) * 8);
  b = *(const u16x8*)(base + (size_t)(n0 + row1) * 1536 + col1);
}

__global__ __launch_bounds__(256) void ktv_partial(const u16* __restrict__ qkv,
                                                   float* __restrict__ Mpart) {
  const int s = blockIdx.x;    // 0..15
  const int bh = blockIdx.y;   // 0..31
  const int b = bh >> 3, h = bh & 7;
  const int t = threadIdx.x;
  __shared__ float smem[4096];           // Kf[32][64] | Vf[32][64]; later Msm[64][64]
  float* Kf = smem;
  float* Vf = smem + 2048;

  const int nsub = t >> 6;               // wave id: n-subset within chunk
  const int slot = t & 63;
  const int d0 = (slot >> 2) * 4;
  const int e0 = (slot & 3) * 16;

  float acc[4][16];
  #pragma unroll
  for (int i = 0; i < 4; ++i)
    #pragma unroll
    for (int j = 0; j < 16; ++j) acc[i][j] = 0.f;

  const u16* base = qkv + (size_t)b * 2048 * 1536;
  const int row0 = t >> 4, part0 = t & 15;
  const int idx1 = 256 + t, row1 = idx1 >> 4, part1 = idx1 & 15;
  float* dst0 = (part0 < 8) ? &Kf[row0 * 64 + part0 * 8] : &Vf[row0 * 64 + (part0 - 8) * 8];
  float* dst1 = (part1 < 8) ? &Kf[row1 * 64 + part1 * 8] : &Vf[row1 * 64 + (part1 - 8) * 8];

  u16x8 cur0, cur1, nxt0, nxt1;
  ktv_load(base, s * 128, h, t, cur0, cur1);

  for (int c = 0; c < 4; ++c) {
    __syncthreads();                     // previous chunk's compute done
    #pragma unroll
    for (int j = 0; j < 8; ++j) dst0[j] = bf2f(cur0[j]);
    #pragma unroll
    for (int j = 0; j < 8; ++j) dst1[j] = bf2f(cur1[j]);
    if (c < 3) ktv_load(base, s * 128 + (c + 1) * 32, h, t, nxt0, nxt1);  // T14: hide HBM under compute
    __syncthreads();
    #pragma unroll
    for (int nn = 0; nn < 8; ++nn) {
      int n = nsub * 8 + nn;
      f32x4 kq = *(const f32x4*)&Kf[n * 64 + d0];
      f32x4 v0 = *(const f32x4*)&Vf[n * 64 + e0];
      f32x4 v1 = *(const f32x4*)&Vf[n * 64 + e0 + 4];
      f32x4 v2 = *(const f32x4*)&Vf[n * 64 + e0 + 8];
      f32x4 v3 = *(const f32x4*)&Vf[n * 64 + e0 + 12];
      #pragma unroll
      for (int i = 0; i < 4; ++i) {
        float ki = kq[i];
        #pragma unroll
        for (int j = 0; j < 4; ++j) {
          acc[i][j]      += ki * v0[j];
          acc[i][4 + j]  += ki * v1[j];
          acc[i][8 + j]  += ki * v2[j];
          acc[i][12 + j] += ki * v3[j];
        }
      }
    }
    cur0 = nxt0; cur1 = nxt1;
  }

  __syncthreads();                       // all compute done; smem reusable as Msm
  float* Msm = smem;
  #pragma unroll
  for (int p = 0; p < 4; ++p) {
    if (nsub == p) {
      #pragma unroll
      for (int i = 0; i < 4; ++i)
        #pragma unroll
        for (int j = 0; j < 16; ++j) {
          float* q = &Msm[(d0 + i) * 64 + e0 + j];
          *q = (p == 0) ? acc[i][j] : (*q + acc[i][j]);
        }
    }
    __syncthreads();
  }
  float4* d4 = (float4*)(Mpart + ((size_t)bh * KTV_SPLIT + s) * 4096);
  const float4* s4 = (const float4*)smem;
  #pragma unroll
  for (int r = 0; r < 4; ++r) d4[t + r * 256] = s4[t + r * 256];
}

// ---- M[bh][d][e] = scale * sum_p Mpart[bh][p][d][e] ----
__global__ __launch_bounds__(256) void reduce_m(const float* __restrict__ Mpart,
                                                float* __restrict__ M, float scale) {
  int i = blockIdx.x * 256 + threadIdx.x;      // 0 .. 32*4096-1
  int bh = i >> 12;
  int off = i & 4095;
  const float* src = Mpart + ((size_t)bh * KTV_SPLIT) * 4096 + off;
  float s = 0.f;
  #pragma unroll
  for (int p = 0; p < KTV_SPLIT; ++p) s += src[(size_t)p * 4096];
  M[i] = s * scale;
}

// ---- Pt[b][c][h*64+d] = sum_e M[bh][d][e] * w_out[h*64+e][c], bf16 ----
__global__ __launch_bounds__(256) void make_pt2(const float* __restrict__ M,
                                                const float* __restrict__ w_out,
                                                u16* __restrict__ Pt) {
  const int ct = blockIdx.x;      // 0..7
  const int bh = blockIdx.y;      // 0..31
  const int b = bh >> 3, h = bh & 7;
  const int t = threadIdx.x;
  __shared__ float Msm[64 * 64];
  {
    const float4* src = (const float4*)(M + (size_t)bh * 4096);
    float4* dst = (float4*)Msm;
    #pragma unroll
    for (int r = 0; r < 4; ++r) dst[t + r * 256] = src[t + r * 256];
  }
  __syncthreads();
  const int c = ct * 64 + (t & 63);
  const int d0 = (t >> 6) * 16;
  float acc[16];
  #pragma unroll
  for (int j = 0; j < 16; ++j) acc[j] = 0.f;
  const float* wcol = w_out + (size_t)h * 64 * 512 + c;
  #pragma unroll 4
  for (int e = 0; e < 64; ++e) {
    float w = wcol[(size_t)e * 512];
    #pragma unroll
    for (int j = 0; j < 16; ++j)
      acc[j] += Msm[(d0 + j) * 64 + e] * w;
  }
  ushort4 ov[4];
  #pragma unroll
  for (int r = 0; r < 4; ++r) {
    ov[r].x = f2bf(acc[r * 4 + 0]);
    ov[r].y = f2bf(acc[r * 4 + 1]);
    ov[r].z = f2bf(acc[r * 4 + 2]);
    ov[r].w = f2bf(acc[r * 4 + 3]);
  }
  ushort4* dst = (ushort4*)(Pt + (size_t)b * 512 * 512 + (size_t)c * 512 + h * 64 + d0);
  #pragma unroll
  for (int r = 0; r < 4; ++r) dst[r] = ov[r];
}

extern "C" void kernel_launch(void* const* d_in, const int* in_sizes, int n_in,
                              void* d_out, int out_size, void* d_ws, size_t ws_size,
                              hipStream_t stream) {
  const float* x     = (const float*)d_in[0];   // [4,2048,512]
  const float* w_qkv = (const float*)d_in[1];   // [512,1536]
  const float* w_out = (const float*)d_in[2];   // [512,512]
  const float* b_out = (const float*)d_in[3];   // [512]
  float* out = (float*)d_out;                   // [4,2048,512] f32
  char* ws = (char*)d_ws;

  u16*   x_bf   = (u16*)(ws);                    // 8 MiB  [8192][512] bf16 (dead after GEMM1)
  u16*   wqkv_t = (u16*)(ws + (8ll << 20));      // 1.5 MiB [1536][512] bf16 (w_qkv^T)
  u16*   qkv    = (u16*)(ws + (10ll << 20));     // 24 MiB [8192][1536] bf16
  float* Mpart  = (float*)(ws + (34ll << 20));   // 8 MiB  [32][16][64][64] f32
  u16*   Pt     = (u16*)(ws + (42ll << 20));     // 2 MiB  [4][512][512] bf16 (P^T per b)
  float* M      = (float*)(ws);                  // 0.5 MiB [32][64][64] f32 (reuses x_bf)

  // 1) x -> bf16 and w_qkv -> transposed bf16 (fused launch)
  prep<<<dim3(4096 + 768), dim3(256), 0, stream>>>(
      (const float4*)x, (ushort4*)x_bf, w_qkv, wqkv_t);
  // 2) qkv = x @ w_qkv   (M=8192, N=1536, K=512), bf16 out
  gemm_bt<false, false, 4><<<dim3(12, 64, 1), dim3(256), 0, stream>>>(
      x_bf, 512, 0ll, wqkv_t, 512, 0ll, qkv, 1536, 0ll, nullptr, 512);
  // 3) partial K^T V per (b,h)
  ktv_partial<<<dim3(KTV_SPLIT, 32), dim3(256), 0, stream>>>(qkv, Mpart);
  // 4) reduce partials (x_bf region is dead now)
  reduce_m<<<dim3(512), dim3(256), 0, stream>>>(Mpart, M, 0.125f / 2048.0f);
  // 5) Pt = (M @ W_out)^T per (b,h)
  make_pt2<<<dim3(8, 32), dim3(256), 0, stream>>>(M, w_out, Pt);
  // 6) out = Q_cat @ P + b_out  (per b: M=2048, N=512, K=512), f32 out, 128x64 tile
  gemm_bt<true, true, 2><<<dim3(8, 16, 4), dim3(256), 0, stream>>>(
      qkv, 1536, 2048ll * 1536, Pt, 512, 512ll * 512, out, 512, 2048ll * 512, b_out, 512);
}